// Round 1
// baseline (258.944 us; speedup 1.0000x reference)
//
#include <hip/hip_runtime.h>
#include <math.h>

#define RES 512
#define NBLOB 2048
#define PRE_STRIDE 12   // floats per preprocessed blob (3x 16B-aligned chunks)

__device__ __forceinline__ float fast_exp2(float x) {
#if __has_builtin(__builtin_amdgcn_exp2f)
    return __builtin_amdgcn_exp2f(x);
#else
    return exp2f(x);
#endif
}

// Per-blob preprocessing: fold rotation, scale, and the exp constant into a
// 2x2 matrix so the inner loop is pure FMA + exp2.
//   g = exp(-0.5*((xr/sx)^2 + (yr/sy)^2)) = exp2(-(u^2 + v^2))
//   u = a*dx + b*dy,  v = d*dx + e*dy,  with K = sqrt(0.5*log2(e)) folded in.
__global__ __launch_bounds__(256) void pre_kernel(const float* __restrict__ blobs,
                                                  float* __restrict__ pre) {
    int i = blockIdx.x * blockDim.x + threadIdx.x;
    if (i >= NBLOB) return;
    const float* bp = blobs + i * 8;
    float posx = bp[0], posy = bp[1];
    float sx = bp[2], sy = bp[3];
    float rot = bp[4];
    float c = cosf(rot), s = sinf(rot);
    const float K = 0.84932184f;  // sqrt(0.5 * log2(e))
    float isx = K / sx, isy = K / sy;
    float* o = pre + i * PRE_STRIDE;
    o[0] = posx;
    o[1] = posy;
    o[2] = c * isx;   // a
    o[3] = s * isx;   // b
    o[4] = -s * isy;  // d
    o[5] = c * isy;   // e
    o[6] = bp[5];     // color r
    o[7] = bp[6];     // color g
    o[8] = bp[7];     // color b
    o[9] = 0.f; o[10] = 0.f; o[11] = 0.f;
}

// One block = 32x16 pixel tile, 256 threads, 2 pixels per thread (rows y0 and
// y0+8 at the same x: shares dx and all blob scalars across both pixels).
// The blob loop index is wave-uniform -> blob loads scalarize to s_load_dwordx4.
__global__ __launch_bounds__(256) void splat_kernel(const float* __restrict__ pre,
                                                    float* __restrict__ out) {
    const int tx = threadIdx.x & 31;
    const int ty = threadIdx.x >> 5;            // 0..7
    const int x  = (blockIdx.x << 5) + tx;      // 16 x-tiles
    const int y0 = (blockIdx.y << 4) + ty;      // 32 y-tiles; rows y0, y0+8
    const float fx  = (x  + 0.5f) * (1.0f / RES);
    const float fy0 = (y0 + 0.5f) * (1.0f / RES);
    const float fy1 = fy0 + (8.0f / RES);

    float a0r = 0.f, a0g = 0.f, a0b = 0.f;
    float a1r = 0.f, a1g = 0.f, a1b = 0.f;

    #pragma unroll 4
    for (int j = 0; j < NBLOB; ++j) {
        const float* p = pre + j * PRE_STRIDE;
        const float bx = p[0], by = p[1];
        const float a  = p[2], b  = p[3];
        const float d  = p[4], e  = p[5];
        const float cr = p[6], cg = p[7], cb = p[8];

        const float dx  = fx  - bx;
        const float dy0 = fy0 - by;
        const float dy1 = fy1 - by;

        const float u0 = a * dx + b * dy0;
        const float v0 = d * dx + e * dy0;
        const float u1 = a * dx + b * dy1;
        const float v1 = d * dx + e * dy1;

        const float g0 = fast_exp2(-(u0 * u0 + v0 * v0));
        const float g1 = fast_exp2(-(u1 * u1 + v1 * v1));

        a0r += g0 * cr; a0g += g0 * cg; a0b += g0 * cb;
        a1r += g1 * cr; a1g += g1 * cg; a1b += g1 * cb;
    }

    const int base0 = (y0 * RES + x) * 3;
    out[base0 + 0] = a0r;
    out[base0 + 1] = a0g;
    out[base0 + 2] = a0b;
    const int base1 = ((y0 + 8) * RES + x) * 3;
    out[base1 + 0] = a1r;
    out[base1 + 1] = a1g;
    out[base1 + 2] = a1b;
}

extern "C" void kernel_launch(void* const* d_in, const int* in_sizes, int n_in,
                              void* d_out, int out_size, void* d_ws, size_t ws_size,
                              hipStream_t stream) {
    const float* blobs = (const float*)d_in[0];
    float* out = (float*)d_out;
    float* pre = (float*)d_ws;

    hipLaunchKernelGGL(pre_kernel, dim3(NBLOB / 256), dim3(256), 0, stream,
                       blobs, pre);

    dim3 grid(RES / 32, RES / 16);   // 16 x 32 = 512 blocks
    hipLaunchKernelGGL(splat_kernel, grid, dim3(256), 0, stream, pre, out);
}

// Round 2
// 253.776 us; speedup vs baseline: 1.0204x; 1.0204x over previous
//
#include <hip/hip_runtime.h>
#include <math.h>

#define RES     512
#define NBLOB   2048
#define TILE_W  32
#define TILE_H  8
#define TX_N    (RES / TILE_W)   // 16
#define TY_N    (RES / TILE_H)   // 64
#define NTILE   (TX_N * TY_N)    // 1024
#define PRE_STRIDE 16            // floats per blob: 9 params + pad + 4 bbox ints
#define CULL_R5 4.9956f          // sqrt(18)/K : 5-sigma-ish cutoff, g<2^-18

__device__ __forceinline__ float fast_exp2(float x) {
#if __has_builtin(__builtin_amdgcn_exp2f)
    return __builtin_amdgcn_exp2f(x);
#else
    return exp2f(x);
#endif
}

// Per-blob preprocessing: fold rotation/scale/exp-constant into 2x2 matrix,
// compute conservative tile-space bbox of the 5-sigma ellipse.
// Threads 0..NTILE-1 also zero the per-tile counts (saves a launch).
__global__ __launch_bounds__(256) void pre_kernel(const float* __restrict__ blobs,
                                                  float* __restrict__ pre,
                                                  int* __restrict__ counts) {
    int i = blockIdx.x * blockDim.x + threadIdx.x;
    if (counts != nullptr && i < NTILE) counts[i] = 0;
    if (i >= NBLOB) return;
    const float* bp = blobs + i * 8;
    float posx = bp[0], posy = bp[1];
    float sx = bp[2], sy = bp[3];
    float rot = bp[4];
    float c = cosf(rot), s = sinf(rot);
    const float K = 0.84932184f;  // sqrt(0.5 * log2(e))
    float isx = K / sx, isy = K / sy;
    float* o = pre + i * PRE_STRIDE;
    o[0] = posx;
    o[1] = posy;
    o[2] = c * isx;   // a
    o[3] = s * isx;   // b
    o[4] = -s * isy;  // d
    o[5] = c * isy;   // e
    o[6] = bp[5];     // color r
    o[7] = bp[6];     // color g
    o[8] = bp[7];     // color b
    o[9] = 0.f; o[10] = 0.f; o[11] = 0.f;

    // bbox half-extents of the ellipse u^2+v^2 <= 18 in UV space
    float hx = CULL_R5 * sqrtf(c * c * sx * sx + s * s * sy * sy);
    float hy = CULL_R5 * sqrtf(s * s * sx * sx + c * c * sy * sy);
    int tx0 = max(0,        (int)floorf(((posx - hx) * RES - 0.5f) * (1.0f / TILE_W)));
    int tx1 = min(TX_N - 1, (int)floorf(((posx + hx) * RES - 0.5f) * (1.0f / TILE_W)));
    int ty0 = max(0,        (int)floorf(((posy - hy) * RES - 0.5f) * (1.0f / TILE_H)));
    int ty1 = min(TY_N - 1, (int)floorf(((posy + hy) * RES - 0.5f) * (1.0f / TILE_H)));
    int* ob = (int*)(o + 12);
    ob[0] = tx0; ob[1] = tx1; ob[2] = ty0; ob[3] = ty1;
}

// One thread per (blob, tile-row): wave-uniform blob (t>>6 constant across a
// 64-lane wave) -> bbox load scalarizes; <=16 atomics per thread, balanced.
__global__ __launch_bounds__(256) void count_kernel(const float* __restrict__ pre,
                                                    int* __restrict__ counts) {
    int t = blockIdx.x * blockDim.x + threadIdx.x;   // 0 .. NBLOB*TY_N-1
    int j = t >> 6;        // blob
    int r = t & 63;        // tile row
    const int* ob = (const int*)(pre + j * PRE_STRIDE + 12);
    int tx0 = ob[0], tx1 = ob[1], ty0 = ob[2], ty1 = ob[3];
    if (r < ty0 || r > ty1) return;
    for (int bx = tx0; bx <= tx1; ++bx)
        atomicAdd(&counts[r * TX_N + bx], 1);
}

// Exclusive prefix sum over 1024 tile counts; init cursors = offsets.
__global__ __launch_bounds__(1024) void scan_kernel(const int* __restrict__ counts,
                                                    int* __restrict__ offsets,
                                                    int* __restrict__ cursors) {
    __shared__ int sh[NTILE];
    int tid = threadIdx.x;
    int my = counts[tid];
    sh[tid] = my;
    __syncthreads();
    for (int d = 1; d < NTILE; d <<= 1) {
        int v = (tid >= d) ? sh[tid - d] : 0;
        __syncthreads();
        sh[tid] += v;
        __syncthreads();
    }
    int excl = sh[tid] - my;
    offsets[tid] = excl;
    cursors[tid] = excl;
}

__global__ __launch_bounds__(256) void fill_kernel(const float* __restrict__ pre,
                                                   int* __restrict__ cursors,
                                                   int* __restrict__ entries) {
    int t = blockIdx.x * blockDim.x + threadIdx.x;
    int j = t >> 6;
    int r = t & 63;
    const int* ob = (const int*)(pre + j * PRE_STRIDE + 12);
    int tx0 = ob[0], tx1 = ob[1], ty0 = ob[2], ty1 = ob[3];
    if (r < ty0 || r > ty1) return;
    for (int bx = tx0; bx <= tx1; ++bx) {
        int slot = atomicAdd(&cursors[r * TX_N + bx], 1);
        entries[slot] = j;
    }
}

// One block per 32x8 tile, 1 pixel per thread, iterate the tile's blob list.
__global__ __launch_bounds__(256) void splat_kernel(const float* __restrict__ pre,
                                                    const int* __restrict__ offsets,
                                                    const int* __restrict__ counts,
                                                    const int* __restrict__ entries,
                                                    float* __restrict__ out) {
    const int t = blockIdx.y * TX_N + blockIdx.x;
    const int start = offsets[t];
    const int n = counts[t];
    const int x = blockIdx.x * TILE_W + (threadIdx.x & 31);
    const int y = blockIdx.y * TILE_H + (threadIdx.x >> 5);
    const float fx = (x + 0.5f) * (1.0f / RES);
    const float fy = (y + 0.5f) * (1.0f / RES);

    float ar = 0.f, ag = 0.f, ab = 0.f;

    #pragma unroll 2
    for (int k = 0; k < n; ++k) {
        int j = entries[start + k];
        j = __builtin_amdgcn_readfirstlane(j);  // uniform: force scalar loads
        const float* p = pre + j * PRE_STRIDE;
        const float dx = fx - p[0];
        const float dy = fy - p[1];
        const float u = p[2] * dx + p[3] * dy;
        const float v = p[4] * dx + p[5] * dy;
        const float g = fast_exp2(-(u * u + v * v));
        ar += g * p[6];
        ag += g * p[7];
        ab += g * p[8];
    }

    const int base = (y * RES + x) * 3;
    out[base + 0] = ar;
    out[base + 1] = ag;
    out[base + 2] = ab;
}

// Fallback (no culling) if ws is too small for the worst-case entries buffer:
// 1024 blocks for occupancy, all blobs per pixel.
__global__ __launch_bounds__(256) void splat_all_kernel(const float* __restrict__ pre,
                                                        float* __restrict__ out) {
    const int x = blockIdx.x * TILE_W + (threadIdx.x & 31);
    const int y = blockIdx.y * TILE_H + (threadIdx.x >> 5);
    const float fx = (x + 0.5f) * (1.0f / RES);
    const float fy = (y + 0.5f) * (1.0f / RES);
    float ar = 0.f, ag = 0.f, ab = 0.f;
    #pragma unroll 4
    for (int j = 0; j < NBLOB; ++j) {
        const float* p = pre + j * PRE_STRIDE;
        const float dx = fx - p[0];
        const float dy = fy - p[1];
        const float u = p[2] * dx + p[3] * dy;
        const float v = p[4] * dx + p[5] * dy;
        const float g = fast_exp2(-(u * u + v * v));
        ar += g * p[6];
        ag += g * p[7];
        ab += g * p[8];
    }
    const int base = (y * RES + x) * 3;
    out[base + 0] = ar;
    out[base + 1] = ag;
    out[base + 2] = ab;
}

extern "C" void kernel_launch(void* const* d_in, const int* in_sizes, int n_in,
                              void* d_out, int out_size, void* d_ws, size_t ws_size,
                              hipStream_t stream) {
    const float* blobs = (const float*)d_in[0];
    float* out = (float*)d_out;

    // ws layout
    char* ws = (char*)d_ws;
    float* pre   = (float*)ws;                       // NBLOB*16 floats = 128 KB
    size_t off   = (size_t)NBLOB * PRE_STRIDE * 4;
    int* counts  = (int*)(ws + off); off += NTILE * 4;
    int* offsets = (int*)(ws + off); off += NTILE * 4;
    int* cursors = (int*)(ws + off); off += NTILE * 4;
    int* entries = (int*)(ws + off);
    size_t need  = off + (size_t)NBLOB * NTILE * 4;  // worst-case entries: 8 MB

    if (ws_size >= need) {
        hipLaunchKernelGGL(pre_kernel, dim3(NBLOB / 256), dim3(256), 0, stream,
                           blobs, pre, counts);
        hipLaunchKernelGGL(count_kernel, dim3(NBLOB * TY_N / 256), dim3(256), 0,
                           stream, pre, counts);
        hipLaunchKernelGGL(scan_kernel, dim3(1), dim3(NTILE), 0, stream,
                           counts, offsets, cursors);
        hipLaunchKernelGGL(fill_kernel, dim3(NBLOB * TY_N / 256), dim3(256), 0,
                           stream, pre, cursors, entries);
        hipLaunchKernelGGL(splat_kernel, dim3(TX_N, TY_N), dim3(256), 0, stream,
                           pre, offsets, counts, entries, out);
    } else {
        hipLaunchKernelGGL(pre_kernel, dim3(NBLOB / 256), dim3(256), 0, stream,
                           blobs, pre, (int*)nullptr);
        hipLaunchKernelGGL(splat_all_kernel, dim3(TX_N, TY_N), dim3(256), 0,
                           stream, pre, out);
    }
}

// Round 3
// 101.885 us; speedup vs baseline: 2.5415x; 2.4908x over previous
//
#include <hip/hip_runtime.h>
#include <math.h>

#define RES     512
#define NBLOB   2048
#define TILE_W  32
#define TILE_H  8
#define TX_N    (RES / TILE_W)   // 16
#define TY_N    (RES / TILE_H)   // 64
#define PRE_STRIDE 16            // floats per blob: 9 params + 3 pad + 4 bbox ints
#define CULL_R5 4.9956f          // sqrt(18)/K : cutoff where g < 2^-18

__device__ __forceinline__ float fast_exp2(float x) {
#if __has_builtin(__builtin_amdgcn_exp2f)
    return __builtin_amdgcn_exp2f(x);
#else
    return exp2f(x);
#endif
}

// Per-blob preprocessing: fold rotation/scale/exp-constant into a 2x2 matrix
// (g = exp2(-(u^2+v^2)) with K = sqrt(0.5*log2 e) folded in), plus the
// conservative tile-space bbox of the cull ellipse u^2+v^2 <= 18.
__global__ __launch_bounds__(256) void pre_kernel(const float* __restrict__ blobs,
                                                  float* __restrict__ pre) {
    int i = blockIdx.x * blockDim.x + threadIdx.x;
    if (i >= NBLOB) return;
    const float* bp = blobs + i * 8;
    float posx = bp[0], posy = bp[1];
    float sx = bp[2], sy = bp[3];
    float rot = bp[4];
    float c = cosf(rot), s = sinf(rot);
    const float K = 0.84932184f;  // sqrt(0.5 * log2(e))
    float isx = K / sx, isy = K / sy;
    float* o = pre + i * PRE_STRIDE;
    o[0] = posx;
    o[1] = posy;
    o[2] = c * isx;   // a
    o[3] = s * isx;   // b
    o[4] = -s * isy;  // d
    o[5] = c * isy;   // e
    o[6] = bp[5];     // color r
    o[7] = bp[6];     // color g
    o[8] = bp[7];     // color b
    o[9] = 0.f; o[10] = 0.f; o[11] = 0.f;

    // bbox half-extents of the ellipse in image space
    float hx = CULL_R5 * sqrtf(c * c * sx * sx + s * s * sy * sy);
    float hy = CULL_R5 * sqrtf(s * s * sx * sx + c * c * sy * sy);
    int tx0 = max(0,        (int)floorf(((posx - hx) * RES - 0.5f) * (1.0f / TILE_W)));
    int tx1 = min(TX_N - 1, (int)floorf(((posx + hx) * RES - 0.5f) * (1.0f / TILE_W)));
    int ty0 = max(0,        (int)floorf(((posy - hy) * RES - 0.5f) * (1.0f / TILE_H)));
    int ty1 = min(TY_N - 1, (int)floorf(((posy + hy) * RES - 0.5f) * (1.0f / TILE_H)));
    int* ob = (int*)(o + 12);
    ob[0] = tx0; ob[1] = tx1; ob[2] = ty0; ob[3] = ty1;
}

// One block per 32x8 tile. Phase 1: the 256 threads test all 2048 blob bboxes
// against this tile and append survivors to an LDS list (one LDS atomic per
// wave via ballot+popc). Phase 2: 1 pixel/thread, iterate the LDS list with
// wave-uniform (scalar) blob loads.
__global__ __launch_bounds__(256) void splat_kernel(const float* __restrict__ pre,
                                                    float* __restrict__ out) {
    __shared__ int sh_cnt;
    __shared__ int sh_list[NBLOB];

    const int tid = threadIdx.x;
    if (tid == 0) sh_cnt = 0;
    __syncthreads();

    const int tx = blockIdx.x;
    const int ty = blockIdx.y;
    const int lane = tid & 63;

    #pragma unroll
    for (int j0 = 0; j0 < NBLOB; j0 += 256) {
        const int j = j0 + tid;
        const int4 ob = *(const int4*)(pre + j * PRE_STRIDE + 12);
        const bool hit = (tx >= ob.x) & (tx <= ob.y) & (ty >= ob.z) & (ty <= ob.w);
        const unsigned long long mask = __ballot(hit);
        const int total = __popcll(mask);
        int base = 0;
        if (lane == 0 && total > 0) base = atomicAdd(&sh_cnt, total);
        base = __builtin_amdgcn_readfirstlane(base);  // lane 0 always active here
        if (hit) {
            const int pos = __popcll(mask & ((1ull << lane) - 1ull));
            sh_list[base + pos] = j;
        }
    }
    __syncthreads();

    const int n = sh_cnt;
    const int x = tx * TILE_W + (tid & 31);
    const int y = ty * TILE_H + (tid >> 5);
    const float fx = (x + 0.5f) * (1.0f / RES);
    const float fy = (y + 0.5f) * (1.0f / RES);

    float ar = 0.f, ag = 0.f, ab = 0.f;

    #pragma unroll 2
    for (int k = 0; k < n; ++k) {
        const int j = __builtin_amdgcn_readfirstlane(sh_list[k]);
        const float* p = pre + j * PRE_STRIDE;
        const float dx = fx - p[0];
        const float dy = fy - p[1];
        const float u = p[2] * dx + p[3] * dy;
        const float v = p[4] * dx + p[5] * dy;
        const float g = fast_exp2(-(u * u + v * v));
        ar += g * p[6];
        ag += g * p[7];
        ab += g * p[8];
    }

    const int base = (y * RES + x) * 3;
    out[base + 0] = ar;
    out[base + 1] = ag;
    out[base + 2] = ab;
}

extern "C" void kernel_launch(void* const* d_in, const int* in_sizes, int n_in,
                              void* d_out, int out_size, void* d_ws, size_t ws_size,
                              hipStream_t stream) {
    const float* blobs = (const float*)d_in[0];
    float* out = (float*)d_out;
    float* pre = (float*)d_ws;   // NBLOB * 16 floats = 128 KB

    hipLaunchKernelGGL(pre_kernel, dim3(NBLOB / 256), dim3(256), 0, stream,
                       blobs, pre);
    hipLaunchKernelGGL(splat_kernel, dim3(TX_N, TY_N), dim3(256), 0, stream,
                       pre, out);
}

// Round 4
// 85.600 us; speedup vs baseline: 3.0250x; 1.1902x over previous
//
#include <hip/hip_runtime.h>
#include <math.h>

#define RES     512
#define NBLOB   2048
#define TILE_W  32
#define TILE_H  8
#define TX_N    (RES / TILE_W)   // 16
#define TY_N    (RES / TILE_H)   // 64
#define PRE_STRIDE 16            // floats per blob: 9 params + 3 pad + 4 bbox ints
#define CHUNK_B 256              // blobs per staging chunk
#define NCHUNK  (NBLOB / CHUNK_B)
#define CULL_R5 4.9956f          // sqrt(18)/K : cutoff where g < 2^-18

__device__ __forceinline__ float fast_exp2(float x) {
#if __has_builtin(__builtin_amdgcn_exp2f)
    return __builtin_amdgcn_exp2f(x);
#else
    return exp2f(x);
#endif
}

// Per-blob preprocessing: fold rotation/scale/exp-constant into a 2x2 matrix
// (g = exp2(-(u^2+v^2)) with K = sqrt(0.5*log2 e) folded in), plus the
// conservative tile-space bbox of the cull ellipse u^2+v^2 <= 18.
// Layout (16 floats): [px py a b | d e cr cg | cb pad pad pad | tx0 tx1 ty0 ty1]
__global__ __launch_bounds__(256) void pre_kernel(const float* __restrict__ blobs,
                                                  float* __restrict__ pre) {
    int i = blockIdx.x * blockDim.x + threadIdx.x;
    if (i >= NBLOB) return;
    const float* bp = blobs + i * 8;
    float posx = bp[0], posy = bp[1];
    float sx = bp[2], sy = bp[3];
    float rot = bp[4];
    float c = cosf(rot), s = sinf(rot);
    const float K = 0.84932184f;  // sqrt(0.5 * log2(e))
    float isx = K / sx, isy = K / sy;
    float* o = pre + i * PRE_STRIDE;
    o[0] = posx;
    o[1] = posy;
    o[2] = c * isx;   // a
    o[3] = s * isx;   // b
    o[4] = -s * isy;  // d
    o[5] = c * isy;   // e
    o[6] = bp[5];     // color r
    o[7] = bp[6];     // color g
    o[8] = bp[7];     // color b
    o[9] = 0.f; o[10] = 0.f; o[11] = 0.f;

    float hx = CULL_R5 * sqrtf(c * c * sx * sx + s * s * sy * sy);
    float hy = CULL_R5 * sqrtf(s * s * sx * sx + c * c * sy * sy);
    int tx0 = max(0,        (int)floorf(((posx - hx) * RES - 0.5f) * (1.0f / TILE_W)));
    int tx1 = min(TX_N - 1, (int)floorf(((posx + hx) * RES - 0.5f) * (1.0f / TILE_W)));
    int ty0 = max(0,        (int)floorf(((posy - hy) * RES - 0.5f) * (1.0f / TILE_H)));
    int ty1 = min(TY_N - 1, (int)floorf(((posy + hy) * RES - 0.5f) * (1.0f / TILE_H)));
    int* ob = (int*)(o + 12);
    ob[0] = tx0; ob[1] = tx1; ob[2] = ty0; ob[3] = ty1;
}

// One block per 32x8 tile. Blobs processed in 8 chunks of 256:
//   cull phase: each thread bbox-tests one blob; survivors copy their 12
//   params into a compacted LDS buffer (ballot+popc slot assignment).
//   splat phase: 1 px/thread iterates the LDS param list at loop-known
//   uniform addresses (broadcast ds_read, pipelines freely — no dependent
//   global/scalar loads in the hot loop).
__global__ __launch_bounds__(256) void splat_kernel(const float* __restrict__ pre,
                                                    float* __restrict__ out) {
    __shared__ int sh_cnt[NCHUNK];
    __shared__ float4 sh_p0[CHUNK_B];   // px py a b
    __shared__ float4 sh_p1[CHUNK_B];   // d e cr cg
    __shared__ float  sh_p2[CHUNK_B];   // cb

    const int tid = threadIdx.x;
    const int lane = tid & 63;
    const int tx = blockIdx.x;
    const int ty = blockIdx.y;

    if (tid < NCHUNK) sh_cnt[tid] = 0;

    const int x = tx * TILE_W + (tid & 31);
    const int y = ty * TILE_H + (tid >> 5);
    const float fx = (x + 0.5f) * (1.0f / RES);
    const float fy = (y + 0.5f) * (1.0f / RES);

    float ar = 0.f, ag = 0.f, ab = 0.f;

    __syncthreads();

    for (int c = 0; c < NCHUNK; ++c) {
        // ---- cull + stage ----
        const int j = c * CHUNK_B + tid;
        const int4 ob = *(const int4*)(pre + j * PRE_STRIDE + 12);
        const bool hit = (tx >= ob.x) & (tx <= ob.y) & (ty >= ob.z) & (ty <= ob.w);
        const unsigned long long mask = __ballot(hit);
        const int total = __popcll(mask);
        int base = 0;
        if (lane == 0 && total > 0) base = atomicAdd(&sh_cnt[c], total);
        base = __builtin_amdgcn_readfirstlane(base);
        if (hit) {
            const int pos = base + __popcll(mask & ((1ull << lane) - 1ull));
            const float4* p4 = (const float4*)(pre + j * PRE_STRIDE);
            sh_p0[pos] = p4[0];
            sh_p1[pos] = p4[1];
            sh_p2[pos] = p4[2].x;
        }
        __syncthreads();

        // ---- splat from LDS ----
        const int n = sh_cnt[c];
        #pragma unroll 4
        for (int k = 0; k < n; ++k) {
            const float4 p0 = sh_p0[k];
            const float4 p1 = sh_p1[k];
            const float  cb = sh_p2[k];
            const float dx = fx - p0.x;
            const float dy = fy - p0.y;
            const float u = p0.z * dx + p0.w * dy;
            const float v = p1.x * dx + p1.y * dy;
            const float g = fast_exp2(-(u * u + v * v));
            ar += g * p1.z;
            ag += g * p1.w;
            ab += g * cb;
        }
        __syncthreads();   // before next chunk overwrites the staging buffers
    }

    const int base = (y * RES + x) * 3;
    out[base + 0] = ar;
    out[base + 1] = ag;
    out[base + 2] = ab;
}

extern "C" void kernel_launch(void* const* d_in, const int* in_sizes, int n_in,
                              void* d_out, int out_size, void* d_ws, size_t ws_size,
                              hipStream_t stream) {
    const float* blobs = (const float*)d_in[0];
    float* out = (float*)d_out;
    float* pre = (float*)d_ws;   // NBLOB * 16 floats = 128 KB

    hipLaunchKernelGGL(pre_kernel, dim3(NBLOB / 256), dim3(256), 0, stream,
                       blobs, pre);
    hipLaunchKernelGGL(splat_kernel, dim3(TX_N, TY_N), dim3(256), 0, stream,
                       pre, out);
}